// Round 3
// baseline (243.710 us; speedup 1.0000x reference)
//
#include <hip/hip_runtime.h>
#include <hip/hip_bf16.h>

// Problem constants
#define BATCH 2
#define SQn 2048
#define SKn 2048
#define DMODEL 1024
#define NH 16
#define HD 64
#define NPOS 257          // 2*128+1
#define RWIN 128          // rel_pos_max_distance
#define RADIUS 256        // local attention radius

typedef __attribute__((ext_vector_type(8))) short bf16x8;
typedef __attribute__((ext_vector_type(4))) float f32x4;

static __device__ __forceinline__ unsigned short f2bf(float f) {
    union { float f; unsigned u; } v; v.f = f;
    unsigned r = (v.u + 0x7FFFu + ((v.u >> 16) & 1u)) >> 16;   // RNE
    return (unsigned short)r;
}

static __device__ __forceinline__ unsigned cvt_pk_bf16(float lo, float hi) {
    unsigned r;
    asm("v_cvt_pk_bf16_f32 %0, %1, %2" : "=v"(r) : "v"(lo), "v"(hi));
    return r;
}

static __device__ __forceinline__ void gl_lds16(const unsigned short* g, unsigned short* l) {
    __builtin_amdgcn_global_load_lds(
        (const __attribute__((address_space(1))) unsigned*)g,
        (__attribute__((address_space(3))) unsigned*)l, 16, 0, 0);
}

// swizzle: distinct chunk slot for rows {i, i+4, i+8, i+12} AND {i, i+2}
// -> ds_read_b128 frag reads are 2-way max (free per m136)
#define SWZ(row) (((row) ^ ((row) >> 2)) & 3)

// ---------------------------------------------------------------------------
// Fused fp32 -> bf16 conversion:
//   Q,K,V (3 x 4M) -> xb;  Wq,Wk,Wv (3 x 1M) -> wb;
//   Wo -> woh[h][n][d] = Wo[n][d*16+h]  (head-sliced repack for gemm_out).
// ---------------------------------------------------------------------------
__global__ __launch_bounds__(256) void convert_kernel(
    const float* __restrict__ Q, const float* __restrict__ K, const float* __restrict__ V,
    const float* __restrict__ Wq, const float* __restrict__ Wk, const float* __restrict__ Wv,
    const float* __restrict__ Wo,
    unsigned short* __restrict__ xb,    // [3][4194304]
    unsigned short* __restrict__ wb,    // [3][1048576]
    unsigned short* __restrict__ woh)   // [16][1024][64]
{
    int i = blockIdx.x * 256 + threadIdx.x;     // float4 index, < 4194304
    if (i < 3145728) {
        int which = i >> 20;
        int off = i & 1048575;
        const float* src = which == 0 ? Q : (which == 1 ? K : V);
        unsigned short* dst = xb + (size_t)which * 4194304;
        float4 v4 = ((const float4*)src)[off];
        ushort4 o4;
        o4.x = f2bf(v4.x); o4.y = f2bf(v4.y); o4.z = f2bf(v4.z); o4.w = f2bf(v4.w);
        ((ushort4*)dst)[off] = o4;
    } else {
        int i2 = i - 3145728;
        int which = i2 >> 18;
        int off = i2 & 262143;
        if (which < 3) {
            const float* src = which == 0 ? Wq : (which == 1 ? Wk : Wv);
            unsigned short* dst = wb + (size_t)which * 1048576;
            float4 v4 = ((const float4*)src)[off];
            ushort4 o4;
            o4.x = f2bf(v4.x); o4.y = f2bf(v4.y); o4.z = f2bf(v4.z); o4.w = f2bf(v4.w);
            ((ushort4*)dst)[off] = o4;
        } else {
            // Wo repack: float4 = Wo[n][c0..c0+3], c=d*16+h (4-aligned c0 ->
            // d fixed, h = (c0&15)+j). Scatter 4 ushorts into woh slabs.
            float4 v4 = ((const float4*)Wo)[off];
            int e0 = off * 4;
            int n  = e0 >> 10;
            int c0 = e0 & 1023;
            int d  = c0 >> 4;
            int h0 = c0 & 15;
            woh[((size_t)(h0 + 0) * 1024 + n) * 64 + d] = f2bf(v4.x);
            woh[((size_t)(h0 + 1) * 1024 + n) * 64 + d] = f2bf(v4.y);
            woh[((size_t)(h0 + 2) * 1024 + n) * 64 + d] = f2bf(v4.z);
            woh[((size_t)(h0 + 3) * 1024 + n) * 64 + d] = f2bf(v4.w);
        }
    }
}

// ---------------------------------------------------------------------------
// QKV bf16 MFMA GEMM: Y = X(4096x1024) @ W(1024x1024)^T, z slab in {0,1,2}.
// 128x128 tile, BK=32, 256 threads (4 waves 2x2 of 64x64).
// z<2 : bf16 head-split [bh][s][hd].  z==2: bf16 [bh][hd][s] via LDS transpose.
// ---------------------------------------------------------------------------
__global__ __launch_bounds__(256) void mfma_gemm(
    const unsigned short* __restrict__ Xall,
    const unsigned short* __restrict__ Wall,
    unsigned short* __restrict__ Yall)
{
    __shared__ unsigned short sA[128 * 32];
    __shared__ unsigned short sB[128 * 32];
    __shared__ unsigned short sT[64 * 136];   // epilogue transpose scratch (z==2)

    const int tid  = threadIdx.x;
    const int wv   = tid >> 6;
    const int lane = tid & 63;
    const int quad = lane >> 4;
    const int l15  = lane & 15;
    const int z    = blockIdx.z;
    const int m0   = blockIdx.x * 128;
    const int n0   = blockIdx.y * 128;
    const int wr   = (wv >> 1) * 64;
    const int wc   = (wv & 1) * 64;

    const unsigned short* X = Xall + (size_t)z * (4096 * 1024);
    const unsigned short* W = Wall + (size_t)z * (1024 * 1024);

    int aoff[4], boff[4];
#pragma unroll
    for (int t = 0; t < 4; ++t) {
        int row = wr + t * 16 + l15;
        aoff[t] = row * 32 + ((quad ^ SWZ(row)) * 8);
        int col = wc + t * 16 + l15;
        boff[t] = col * 32 + ((quad ^ SWZ(col)) * 8);
    }

    int srow[2], scg[2], sf[2];
#pragma unroll
    for (int r = 0; r < 2; ++r) {
        int f = r * 256 + tid;
        sf[r] = f;
        srow[r] = f >> 2;
        scg[r] = (f & 3) ^ SWZ(srow[r]);
    }

    f32x4 acc[4][4];
#pragma unroll
    for (int i = 0; i < 4; ++i)
#pragma unroll
        for (int j = 0; j < 4; ++j)
            acc[i][j] = (f32x4){0.f, 0.f, 0.f, 0.f};

    for (int k0 = 0; k0 < 1024; k0 += 32) {
        __syncthreads();
#pragma unroll
        for (int r = 0; r < 2; ++r) {
            gl_lds16(X + (size_t)(m0 + srow[r]) * 1024 + k0 + scg[r] * 8, &sA[sf[r] * 8]);
            gl_lds16(W + (size_t)(n0 + srow[r]) * 1024 + k0 + scg[r] * 8, &sB[sf[r] * 8]);
        }
        __syncthreads();

        bf16x8 af[4], bfr[4];
#pragma unroll
        for (int t = 0; t < 4; ++t) af[t]  = *(const bf16x8*)&sA[aoff[t]];
#pragma unroll
        for (int t = 0; t < 4; ++t) bfr[t] = *(const bf16x8*)&sB[boff[t]];
#pragma unroll
        for (int i = 0; i < 4; ++i)
#pragma unroll
            for (int j = 0; j < 4; ++j)
                acc[i][j] = __builtin_amdgcn_mfma_f32_16x16x32_bf16(af[i], bfr[j], acc[i][j], 0, 0, 0);
    }

    unsigned short* Y = Yall + (size_t)z * (4096 * 1024);
    const int b_ = m0 >> 11;            // batch (tile never straddles)
    const int s0 = m0 & (SQn - 1);

    if (z < 2) {
        // head-split [bh][s][hd]
#pragma unroll
        for (int i = 0; i < 4; ++i) {
            int mbase = s0 + wr + i * 16 + quad * 4;
#pragma unroll
            for (int j = 0; j < 4; ++j) {
                int col = n0 + wc + j * 16 + l15;
                int h = col >> 6, dd = col & 63;
                unsigned short* yb = Y + (((size_t)(b_ * NH + h) * SQn) << 6) + dd;
#pragma unroll
                for (int r = 0; r < 4; ++r)
                    yb[(size_t)(mbase + r) << 6] = f2bf(acc[i][j][r]);
            }
        }
    } else {
        // V: [bh][hd][s] via LDS transpose, coalesced dwordx4 stores.
#pragma unroll
        for (int hh = 0; hh < 2; ++hh) {
            __syncthreads();
            if ((wv & 1) == hh) {
#pragma unroll
                for (int i = 0; i < 4; ++i) {
                    int mloc = wr + i * 16 + quad * 4;
#pragma unroll
                    for (int j = 0; j < 4; ++j) {
                        ushort4 pk;
                        pk.x = f2bf(acc[i][j][0]);
                        pk.y = f2bf(acc[i][j][1]);
                        pk.z = f2bf(acc[i][j][2]);
                        pk.w = f2bf(acc[i][j][3]);
                        *(ushort4*)&sT[(j * 16 + l15) * 136 + mloc] = pk;
                    }
                }
            }
            __syncthreads();
            int h = (n0 >> 6) + hh;
            unsigned short* yb = Y + ((size_t)(b_ * NH + h) * HD) * SKn + s0;
#pragma unroll
            for (int it = 0; it < 4; ++it) {
                int u = it * 256 + tid;
                int dd = u >> 4, mc = u & 15;
                uint4 val = *(const uint4*)&sT[dd * 136 + mc * 8];
                *(uint4*)(yb + (size_t)dd * SKn + mc * 8) = val;
            }
        }
    }
}

// ---------------------------------------------------------------------------
// Output-projection GEMM v2, head-major K order:
//   out[m][n] = sum_h sum_d aoh[b*16+h][s][d] * woh[h][n][d]
// aoh [bh][s][64] and woh [h][n][64] are both K-major contiguous.
// 64x128 tile -> 512 blocks (2/CU); h-loop(16) x k0 in {0,32}; acc[2][4].
// ---------------------------------------------------------------------------
__global__ __launch_bounds__(256) void gemm_out(
    const unsigned short* __restrict__ aoh,
    const unsigned short* __restrict__ woh,
    float* __restrict__ Y)
{
    __shared__ unsigned short sA[64 * 32];
    __shared__ unsigned short sB[128 * 32];

    const int tid  = threadIdx.x;
    const int wv   = tid >> 6;
    const int lane = tid & 63;
    const int quad = lane >> 4;
    const int l15  = lane & 15;
    const int m0   = blockIdx.x * 64;
    const int n0   = blockIdx.y * 128;
    const int wr   = (wv >> 1) * 32;
    const int wc   = (wv & 1) * 64;
    const int b_   = m0 >> 11;
    const int s0   = m0 & (SQn - 1);

    int aoff[2], boff[4];
#pragma unroll
    for (int i = 0; i < 2; ++i) {
        int row = wr + i * 16 + l15;
        aoff[i] = row * 32 + ((quad ^ SWZ(row)) * 8);
    }
#pragma unroll
    for (int j = 0; j < 4; ++j) {
        int col = wc + j * 16 + l15;
        boff[j] = col * 32 + ((quad ^ SWZ(col)) * 8);
    }

    const int arow = tid >> 2;
    const int acs  = (tid & 3) ^ SWZ(arow);
    int bf_[2], brow[2], bcs[2];
#pragma unroll
    for (int r = 0; r < 2; ++r) {
        int f = r * 256 + tid;
        bf_[r] = f; brow[r] = f >> 2; bcs[r] = (f & 3) ^ SWZ(brow[r]);
    }

    f32x4 acc[2][4];
#pragma unroll
    for (int i = 0; i < 2; ++i)
#pragma unroll
        for (int j = 0; j < 4; ++j)
            acc[i][j] = (f32x4){0.f, 0.f, 0.f, 0.f};

    for (int h = 0; h < NH; ++h) {
        const unsigned short* Ah = aoh + ((size_t)(b_ * NH + h) * SQn + s0) * HD;
        const unsigned short* Bh = woh + ((size_t)h * 1024 + n0) * HD;
#pragma unroll
        for (int k0 = 0; k0 < 64; k0 += 32) {
            __syncthreads();
            gl_lds16(Ah + (size_t)arow * HD + k0 + acs * 8, &sA[tid * 8]);
#pragma unroll
            for (int r = 0; r < 2; ++r)
                gl_lds16(Bh + (size_t)brow[r] * HD + k0 + bcs[r] * 8, &sB[bf_[r] * 8]);
            __syncthreads();

            bf16x8 af[2], bfr[4];
#pragma unroll
            for (int i = 0; i < 2; ++i) af[i]  = *(const bf16x8*)&sA[aoff[i]];
#pragma unroll
            for (int j = 0; j < 4; ++j) bfr[j] = *(const bf16x8*)&sB[boff[j]];
#pragma unroll
            for (int i = 0; i < 2; ++i)
#pragma unroll
                for (int j = 0; j < 4; ++j)
                    acc[i][j] = __builtin_amdgcn_mfma_f32_16x16x32_bf16(af[i], bfr[j], acc[i][j], 0, 0, 0);
        }
    }

#pragma unroll
    for (int i = 0; i < 2; ++i) {
        int mbase = m0 + wr + i * 16 + quad * 4;
#pragma unroll
        for (int j = 0; j < 4; ++j) {
            int col = n0 + wc + j * 16 + l15;
#pragma unroll
            for (int r = 0; r < 4; ++r)
                Y[(size_t)(mbase + r) * DMODEL + col] = acc[i][j][r];
        }
    }
}

// ---------------------------------------------------------------------------
// E (P x D) fp32 -> relTb[h][p][d] bf16, rel[h][p][d] = E[p, d*NH + h]
// ---------------------------------------------------------------------------
__global__ __launch_bounds__(256) void relt_kernel(
    const float* __restrict__ E, unsigned short* __restrict__ relTb)
{
    int idx = blockIdx.x * 256 + threadIdx.x;
    const int total = NH * NPOS * HD;
    if (idx < total) {
        int d = idx & (HD - 1);
        int p = (idx >> 6) % NPOS;
        int h = idx / (NPOS * HD);
        relTb[idx] = f2bf(E[(size_t)p * DMODEL + d * NH + h]);
    }
}

// ---------------------------------------------------------------------------
// MFMA flash-style local attention, v7: BARRIER-FREE main loop.
// v5/v6 post-mortem: occupancy was never the constraint; the kernel is
// softmax-VALU-bound (~40K cy/CU of exp work ~= measured VALUBusy) with the
// per-tile __syncthreads locking all 4 waves into bursty phases (27% VALU).
// v7: (1) no LDS staging / no barriers in the main loop -- K and V frags
// load global->register directly (L2-resident per XCD; sP is wave-private,
// sq8 read-only); register-rotating prefetch keeps loads in flight across
// the next compute phase with counted vmcnt. Waves drift freely -> VALU/
// MFMA/mem phases overlap across 16 waves/CU. (2) swapped QK^T mfma(kf,a)
// -> lane holds 4 k-contiguous P values of ONE q row: P->bf16 via 2x
// v_cvt_pk_bf16_f32 + ds_write_b64 (vs 16 f2bf ops + 4 stores), stride-1
// sq8 reads, scalar lacc/bias. (3) exp2-direct with log2-folded scales.
// ---------------------------------------------------------------------------
#define BIAS_S2 0.0014089565402528222f   // (1/1024)/ln2
#define SC2     0.1803368801111204f      // 0.125/ln2

__global__ __launch_bounds__(256, 4) void attn_mfma(
    const unsigned short* __restrict__ q,
    const unsigned short* __restrict__ k,
    const unsigned short* __restrict__ vT,
    const unsigned short* __restrict__ relTb,
    unsigned short* __restrict__ aoh)
{
    __shared__ unsigned short sK[64 * 64];     // qrel-phase staging only
    __shared__ unsigned short sP[4][16 * 72];  // per-wave P tile, row=q stride 72
    __shared__ signed char    sq8[64 * 260];   // int8 bias; first 8KB doubles as sQ
    unsigned short* const sQ = (unsigned short*)sq8;

    const int tid  = threadIdx.x;
    const int w    = tid >> 6;
    const int lane = tid & 63;
    const int quad = lane >> 4;
    const int l15  = lane & 15;
    // XCD-aware block swizzle (blockIdx%8 ~ XCD round-robin heuristic)
    const int xcd  = blockIdx.x & 7;
    const int sidx = blockIdx.x >> 3;
    const int bh   = (xcd << 2) | (sidx >> 5);
    const int q0   = (sidx & 31) << 6;
    const int h    = bh & (NH - 1);

    // hoisted staging descriptors (two 16B issues per thread)
    const int f1 = tid,       row1 = f1 >> 3;
    const int c1 = ((f1 & 7) ^ (row1 & 7)) * 8;
    const int f2 = 256 + tid, row2 = f2 >> 3;
    const int c2 = ((f2 & 7) ^ (row2 & 7)) * 8;

    // ---- stage Q tile (into the region later overwritten by sq8) ----
    {
        const unsigned short* gq = q + ((size_t)bh * SQn + q0) * HD;
        gl_lds16(gq + row1 * HD + c1, &sQ[f1 * 8]);
        gl_lds16(gq + row2 * HD + c2, &sQ[f2 * 8]);
    }
    __syncthreads();

    const int qrow = w * 16 + l15;
    const int qs = (quad ^ (qrow & 7)) * 8;
    bf16x8 a0 = *(const bf16x8*)&sQ[qrow * 64 + qs];
    bf16x8 a1 = *(const bf16x8*)&sQ[qrow * 64 + (qs ^ 32)];

    // ---- qrel phase: int8-encode qrel*0.125 in 1/1024 units ----
    // (first c5 iteration's barrier pair guarantees every wave has read its
    //  a0/a1 from sQ before any sq8 write lands on the aliased region)
    const int myrow = w * 16 + quad * 4;
    for (int c5 = 0; c5 < 5; ++c5) {
        __syncthreads();
        const unsigned short* gr = relTb + ((size_t)h * NPOS + c5 * 64) * HD;
        gl_lds16(gr + row1 * HD + c1, &sK[f1 * 8]);
        gl_lds16(gr + row2 * HD + c2, &sK[f2 * 8]);
        __syncthreads();
#pragma unroll
        for (int t = 0; t < 4; ++t) {
            int prow = t * 16 + l15;
            int ks = (quad ^ (prow & 7)) * 8;
            bf16x8 b0 = *(const bf16x8*)&sK[prow * 64 + ks];
            bf16x8 b1 = *(const bf16x8*)&sK[prow * 64 + (ks ^ 32)];
            f32x4 cc = {0.f, 0.f, 0.f, 0.f};
            cc = __builtin_amdgcn_mfma_f32_16x16x32_bf16(a0, b0, cc, 0, 0, 0);
            cc = __builtin_amdgcn_mfma_f32_16x16x32_bf16(a1, b1, cc, 0, 0, 0);
            int pos = c5 * 64 + t * 16 + l15;
            if (pos < NPOS) {
#pragma unroll
                for (int r = 0; r < 4; ++r) {
                    int iq = (int)rintf(cc[r] * 128.0f);
                    iq = iq < -127 ? -127 : (iq > 127 ? 127 : iq);
                    sq8[(myrow + r) * 260 + pos] = (signed char)iq;
                }
            }
        }
    }
    __syncthreads();
    // ---- no more __syncthreads from here on: sP is wave-private, sq8 RO ----

    const int qr = w * 16 + l15;            // this lane's q row (softmax view)
    const int e2 = quad * 4 - l15;
    const float bias0   = (float)sq8[qr * 260 + 0]   * BIAS_S2;
    const float bias256 = (float)sq8[qr * 260 + 256] * BIAS_S2;

    const int lo = (q0 - RADIUS) > 0 ? (q0 - RADIUS) : 0;
    const int hi = (q0 + 63 + RADIUS) < (SKn - 1) ? (q0 + 63 + RADIUS) : (SKn - 1);
    const int nt = ((hi - lo) >> 6) + 1;

    const unsigned short* kg = k  + (size_t)bh * SKn * HD;
    const unsigned short* vg = vT + (size_t)bh * HD * SKn;

    float lacc = 0.f;
    f32x4 o[4];
#pragma unroll
    for (int t = 0; t < 4; ++t) o[t] = (f32x4){0.f, 0.f, 0.f, 0.f};

    // prologue: K frags (oldest vmcnt) then V frags for tile 0, direct to regs
    bf16x8 kc0[4], kc1[4], vf0[4], vf1[4];
#pragma unroll
    for (int t = 0; t < 4; ++t) {
        const unsigned short* krow = kg + (size_t)(lo + t * 16 + l15) * HD;
        kc0[t] = *(const bf16x8*)(krow + quad * 8);
        kc1[t] = *(const bf16x8*)(krow + 32 + quad * 8);
    }
#pragma unroll
    for (int t = 0; t < 4; ++t) {
        const unsigned short* vrow = vg + (size_t)(t * 16 + l15) * SKn + lo;
        vf0[t] = *(const bf16x8*)(vrow + quad * 8);
        vf1[t] = *(const bf16x8*)(vrow + 32 + quad * 8);
    }

    for (int kt = 0; kt < nt; ++kt) {
        const int kb  = lo + (kt << 6);
        const int kb2 = (kt + 1 < nt) ? kb + 64 : kb;   // clamped prefetch base
        const int dtbase = kb - q0 - w * 16;

#pragma unroll
        for (int t = 0; t < 4; ++t) {
            const int dt  = dtbase + t * 16;             // wave-uniform
            const int spw = l15 * 72 + t * 16 + quad * 4;
            const unsigned short* krow = kg + (size_t)(kb2 + t * 16 + l15) * HD;
            if (dt <= -272 || dt >= 272) {
                kc0[t] = *(const bf16x8*)(krow + quad * 8);
                kc1[t] = *(const bf16x8*)(krow + 32 + quad * 8);
                *(uint2*)&sP[w][spw] = (uint2){0u, 0u};
            } else {
                // swapped QK^T: S^T tile; lane holds q=qr, k=t*16+quad*4+r
                f32x4 sc = {0.f, 0.f, 0.f, 0.f};
                sc = __builtin_amdgcn_mfma_f32_16x16x32_bf16(kc0[t], a0, sc, 0, 0, 0);
                sc = __builtin_amdgcn_mfma_f32_16x16x32_bf16(kc1[t], a1, sc, 0, 0, 0);
                // reload this t's K frags for the next tile (regs consumed)
                kc0[t] = *(const bf16x8*)(krow + quad * 8);
                kc1[t] = *(const bf16x8*)(krow + 32 + quad * 8);

                float pv[4];
                if (dt >= -112 && dt <= 112) {
                    const int idx0 = qr * 260 + dt + e2 + 128;
#pragma unroll
                    for (int r = 0; r < 4; ++r)
                        pv[r] = __builtin_amdgcn_exp2f(
                            fmaf(sc[r], SC2, (float)sq8[idx0 + r] * BIAS_S2));
                } else if (dt >= -240 && dt <= -144) {   // flat p=0, all in-window
#pragma unroll
                    for (int r = 0; r < 4; ++r)
                        pv[r] = __builtin_amdgcn_exp2f(fmaf(sc[r], SC2, bias0));
                } else if (dt >= 144 && dt <= 240) {     // flat p=256, all in-window
#pragma unroll
                    for (int r = 0; r < 4; ++r)
                        pv[r] = __builtin_amdgcn_exp2f(fmaf(sc[r], SC2, bias256));
                } else {    // boundary tiles: mask + clip per element
#pragma unroll
                    for (int r = 0; r < 4; ++r) {
                        int d = dt + e2 + r;
                        bool in = (unsigned)(d + RADIUS) <= 2u * RADIUS;
                        int p = d < -RWIN ? 0 : (d > RWIN ? 2 * RWIN : d + RWIN);
                        float bf = (float)sq8[qr * 260 + p] * BIAS_S2;
                        float e = __builtin_amdgcn_exp2f(fmaf(sc[r], SC2, bf));
                        pv[r] = in ? e : 0.0f;
                    }
                }
                unsigned pk0 = cvt_pk_bf16(pv[0], pv[1]);
                unsigned pk1 = cvt_pk_bf16(pv[2], pv[3]);
                *(uint2*)&sP[w][spw] = (uint2){pk0, pk1};
                // lacc from the ROUNDED values (denominator matches numerator)
                union { unsigned u; float f; } u0, u1, u2, u3;
                u0.u = pk0 << 16; u1.u = pk0 & 0xFFFF0000u;
                u2.u = pk1 << 16; u3.u = pk1 & 0xFFFF0000u;
                lacc += (u0.f + u1.f) + (u2.f + u3.f);
            }
        }

        // PV (wave-local lgkmcnt orders sP write->read; no barrier needed)
        bf16x8 p0 = *(const bf16x8*)&sP[w][l15 * 72 + quad * 8];
        bf16x8 p1 = *(const bf16x8*)&sP[w][l15 * 72 + 32 + quad * 8];
#pragma unroll
        for (int t = 0; t < 4; ++t) {
            o[t] = __builtin_amdgcn_mfma_f32_16x16x32_bf16(p0, vf0[t], o[t], 0, 0, 0);
            o[t] = __builtin_amdgcn_mfma_f32_16x16x32_bf16(p1, vf1[t], o[t], 0, 0, 0);
        }
        // reload V frags for next tile (consumed above)
#pragma unroll
        for (int t = 0; t < 4; ++t) {
            const unsigned short* vrow = vg + (size_t)(t * 16 + l15) * SKn + kb2;
            vf0[t] = *(const bf16x8*)(vrow + quad * 8);
            vf1[t] = *(const bf16x8*)(vrow + 32 + quad * 8);
        }
    }

    // row sums: lane's lacc covers k = {t*16+quad*4+r} for row qr.
    // reduce over quad (lane bits 4,5); then redistribute: epilogue lane
    // needs rows quad*4+r -> fetch inverse from lane id (quad*4+r).
    float l = lacc;
    l += __shfl_xor(l, 16);
    l += __shfl_xor(l, 32);
    float li = 1.0f / l;
    float linv[4];
#pragma unroll
    for (int r = 0; r < 4; ++r) linv[r] = __shfl(li, quad * 4 + r);

    // epilogue: per-block dense aoh[bh][s][d] (8 KB contiguous per block)
    unsigned short* ob = aoh + ((size_t)bh * SQn + q0) * HD;
#pragma unroll
    for (int t = 0; t < 4; ++t) {
#pragma unroll
        for (int r = 0; r < 4; ++r) {
            int irow = w * 16 + quad * 4 + r;
            ob[irow * HD + t * 16 + l15] = f2bf(o[t][r] * linv[r]);
        }
    }
}

// ---------------------------------------------------------------------------
extern "C" void kernel_launch(void* const* d_in, const int* in_sizes, int n_in,
                              void* d_out, int out_size, void* d_ws, size_t ws_size,
                              hipStream_t stream) {
    const float* Q  = (const float*)d_in[0];
    const float* K  = (const float*)d_in[1];
    const float* V  = (const float*)d_in[2];
    const float* Wq = (const float*)d_in[3];
    const float* Wk = (const float*)d_in[4];
    const float* Wv = (const float*)d_in[5];
    const float* Wo = (const float*)d_in[6];
    const float* E  = (const float*)d_in[7];
    float* out = (float*)d_out;

    char* p = (char*)d_ws;
    unsigned short* xb    = (unsigned short*)p; p += (size_t)24 << 20;  // [3][4M] bf16
    unsigned short* wb    = (unsigned short*)p; p += (size_t)6  << 20;  // [3][1M] bf16
    unsigned short* woh   = (unsigned short*)p; p += (size_t)2  << 20;  // [16][1024][64]
    unsigned short* head  = (unsigned short*)p; p += (size_t)24 << 20;  // q,k,vT bf16
    unsigned short* relTb = (unsigned short*)p; p += (size_t)1  << 20;
    unsigned short* aoh   = (unsigned short*)p;                          // 8 MB

    unsigned short* qb  = head;
    unsigned short* kb  = head + 4194304;
    unsigned short* vTb = head + 8388608;

    dim3 bb(256);
    convert_kernel<<<dim3(16384), bb, 0, stream>>>(Q, K, V, Wq, Wk, Wv, Wo, xb, wb, woh);
    relt_kernel<<<dim3(1028), bb, 0, stream>>>(E, relTb);
    mfma_gemm<<<dim3(32, 8, 3), bb, 0, stream>>>(xb, wb, head);
    attn_mfma<<<dim3(BATCH * NH * (SQn / 64)), bb, 0, stream>>>(qb, kb, vTb, relTb, aoh);
    gemm_out<<<dim3(64, 8), bb, 0, stream>>>(aoh, woh, out);
}

// Round 4
// 206.695 us; speedup vs baseline: 1.1791x; 1.1791x over previous
//
#include <hip/hip_runtime.h>
#include <hip/hip_bf16.h>

// Problem constants
#define BATCH 2
#define SQn 2048
#define SKn 2048
#define DMODEL 1024
#define NH 16
#define HD 64
#define NPOS 257          // 2*128+1
#define RWIN 128          // rel_pos_max_distance
#define RADIUS 256        // local attention radius

typedef __attribute__((ext_vector_type(8))) short bf16x8;
typedef __attribute__((ext_vector_type(4))) float f32x4;

static __device__ __forceinline__ unsigned short f2bf(float f) {
    union { float f; unsigned u; } v; v.f = f;
    unsigned r = (v.u + 0x7FFFu + ((v.u >> 16) & 1u)) >> 16;   // RNE
    return (unsigned short)r;
}
static __device__ __forceinline__ float bf2f(unsigned short b) {
    union { unsigned u; float f; } v; v.u = ((unsigned)b) << 16;
    return v.f;
}

static __device__ __forceinline__ void gl_lds16(const unsigned short* g, unsigned short* l) {
    __builtin_amdgcn_global_load_lds(
        (const __attribute__((address_space(1))) unsigned*)g,
        (__attribute__((address_space(3))) unsigned*)l, 16, 0, 0);
}

// swizzle: distinct chunk slot for rows {i, i+4, i+8, i+12} AND {i, i+2}
// -> ds_read_b128 frag reads are 2-way max (free per m136)
#define SWZ(row) (((row) ^ ((row) >> 2)) & 3)

// ---------------------------------------------------------------------------
// Fused fp32 -> bf16 conversion:
//   Q,K,V (3 x 4M) -> xb;  Wq,Wk,Wv (3 x 1M) -> wb;
//   Wo -> woh[h][n][d] = Wo[n][d*16+h]  (head-sliced repack for gemm_out).
// ---------------------------------------------------------------------------
__global__ __launch_bounds__(256) void convert_kernel(
    const float* __restrict__ Q, const float* __restrict__ K, const float* __restrict__ V,
    const float* __restrict__ Wq, const float* __restrict__ Wk, const float* __restrict__ Wv,
    const float* __restrict__ Wo,
    unsigned short* __restrict__ xb,    // [3][4194304]
    unsigned short* __restrict__ wb,    // [3][1048576]
    unsigned short* __restrict__ woh)   // [16][1024][64]
{
    int i = blockIdx.x * 256 + threadIdx.x;     // float4 index, < 4194304
    if (i < 3145728) {
        int which = i >> 20;
        int off = i & 1048575;
        const float* src = which == 0 ? Q : (which == 1 ? K : V);
        unsigned short* dst = xb + (size_t)which * 4194304;
        float4 v4 = ((const float4*)src)[off];
        ushort4 o4;
        o4.x = f2bf(v4.x); o4.y = f2bf(v4.y); o4.z = f2bf(v4.z); o4.w = f2bf(v4.w);
        ((ushort4*)dst)[off] = o4;
    } else {
        int i2 = i - 3145728;
        int which = i2 >> 18;
        int off = i2 & 262143;
        if (which < 3) {
            const float* src = which == 0 ? Wq : (which == 1 ? Wk : Wv);
            unsigned short* dst = wb + (size_t)which * 1048576;
            float4 v4 = ((const float4*)src)[off];
            ushort4 o4;
            o4.x = f2bf(v4.x); o4.y = f2bf(v4.y); o4.z = f2bf(v4.z); o4.w = f2bf(v4.w);
            ((ushort4*)dst)[off] = o4;
        } else {
            // Wo repack: float4 = Wo[n][c0..c0+3], c=d*16+h (4-aligned c0 ->
            // d fixed, h = (c0&15)+j). Scatter 4 ushorts into woh slabs.
            float4 v4 = ((const float4*)Wo)[off];
            int e0 = off * 4;
            int n  = e0 >> 10;
            int c0 = e0 & 1023;
            int d  = c0 >> 4;
            int h0 = c0 & 15;
            woh[((size_t)(h0 + 0) * 1024 + n) * 64 + d] = f2bf(v4.x);
            woh[((size_t)(h0 + 1) * 1024 + n) * 64 + d] = f2bf(v4.y);
            woh[((size_t)(h0 + 2) * 1024 + n) * 64 + d] = f2bf(v4.z);
            woh[((size_t)(h0 + 3) * 1024 + n) * 64 + d] = f2bf(v4.w);
        }
    }
}

// ---------------------------------------------------------------------------
// QKV bf16 MFMA GEMM: Y = X(4096x1024) @ W(1024x1024)^T, z slab in {0,1,2}.
// 128x128 tile, BK=32, 256 threads (4 waves 2x2 of 64x64).
// z<2 : bf16 head-split [bh][s][hd].  z==2: bf16 [bh][hd][s] via LDS transpose.
// ---------------------------------------------------------------------------
__global__ __launch_bounds__(256) void mfma_gemm(
    const unsigned short* __restrict__ Xall,
    const unsigned short* __restrict__ Wall,
    unsigned short* __restrict__ Yall)
{
    __shared__ unsigned short sA[128 * 32];
    __shared__ unsigned short sB[128 * 32];
    __shared__ unsigned short sT[64 * 136];   // epilogue transpose scratch (z==2)

    const int tid  = threadIdx.x;
    const int wv   = tid >> 6;
    const int lane = tid & 63;
    const int quad = lane >> 4;
    const int l15  = lane & 15;
    const int z    = blockIdx.z;
    const int m0   = blockIdx.x * 128;
    const int n0   = blockIdx.y * 128;
    const int wr   = (wv >> 1) * 64;
    const int wc   = (wv & 1) * 64;

    const unsigned short* X = Xall + (size_t)z * (4096 * 1024);
    const unsigned short* W = Wall + (size_t)z * (1024 * 1024);

    int aoff[4], boff[4];
#pragma unroll
    for (int t = 0; t < 4; ++t) {
        int row = wr + t * 16 + l15;
        aoff[t] = row * 32 + ((quad ^ SWZ(row)) * 8);
        int col = wc + t * 16 + l15;
        boff[t] = col * 32 + ((quad ^ SWZ(col)) * 8);
    }

    int srow[2], scg[2], sf[2];
#pragma unroll
    for (int r = 0; r < 2; ++r) {
        int f = r * 256 + tid;
        sf[r] = f;
        srow[r] = f >> 2;
        scg[r] = (f & 3) ^ SWZ(srow[r]);
    }

    f32x4 acc[4][4];
#pragma unroll
    for (int i = 0; i < 4; ++i)
#pragma unroll
        for (int j = 0; j < 4; ++j)
            acc[i][j] = (f32x4){0.f, 0.f, 0.f, 0.f};

    for (int k0 = 0; k0 < 1024; k0 += 32) {
        __syncthreads();
#pragma unroll
        for (int r = 0; r < 2; ++r) {
            gl_lds16(X + (size_t)(m0 + srow[r]) * 1024 + k0 + scg[r] * 8, &sA[sf[r] * 8]);
            gl_lds16(W + (size_t)(n0 + srow[r]) * 1024 + k0 + scg[r] * 8, &sB[sf[r] * 8]);
        }
        __syncthreads();

        bf16x8 af[4], bfr[4];
#pragma unroll
        for (int t = 0; t < 4; ++t) af[t]  = *(const bf16x8*)&sA[aoff[t]];
#pragma unroll
        for (int t = 0; t < 4; ++t) bfr[t] = *(const bf16x8*)&sB[boff[t]];
#pragma unroll
        for (int i = 0; i < 4; ++i)
#pragma unroll
            for (int j = 0; j < 4; ++j)
                acc[i][j] = __builtin_amdgcn_mfma_f32_16x16x32_bf16(af[i], bfr[j], acc[i][j], 0, 0, 0);
    }

    unsigned short* Y = Yall + (size_t)z * (4096 * 1024);
    const int b_ = m0 >> 11;            // batch (tile never straddles)
    const int s0 = m0 & (SQn - 1);

    if (z < 2) {
        // head-split [bh][s][hd]
#pragma unroll
        for (int i = 0; i < 4; ++i) {
            int mbase = s0 + wr + i * 16 + quad * 4;
#pragma unroll
            for (int j = 0; j < 4; ++j) {
                int col = n0 + wc + j * 16 + l15;
                int h = col >> 6, dd = col & 63;
                unsigned short* yb = Y + (((size_t)(b_ * NH + h) * SQn) << 6) + dd;
#pragma unroll
                for (int r = 0; r < 4; ++r)
                    yb[(size_t)(mbase + r) << 6] = f2bf(acc[i][j][r]);
            }
        }
    } else {
        // V: [bh][hd][s] via LDS transpose, coalesced dwordx4 stores.
#pragma unroll
        for (int hh = 0; hh < 2; ++hh) {
            __syncthreads();
            if ((wv & 1) == hh) {
#pragma unroll
                for (int i = 0; i < 4; ++i) {
                    int mloc = wr + i * 16 + quad * 4;
#pragma unroll
                    for (int j = 0; j < 4; ++j) {
                        ushort4 pk;
                        pk.x = f2bf(acc[i][j][0]);
                        pk.y = f2bf(acc[i][j][1]);
                        pk.z = f2bf(acc[i][j][2]);
                        pk.w = f2bf(acc[i][j][3]);
                        *(ushort4*)&sT[(j * 16 + l15) * 136 + mloc] = pk;
                    }
                }
            }
            __syncthreads();
            int h = (n0 >> 6) + hh;
            unsigned short* yb = Y + ((size_t)(b_ * NH + h) * HD) * SKn + s0;
#pragma unroll
            for (int it = 0; it < 4; ++it) {
                int u = it * 256 + tid;
                int dd = u >> 4, mc = u & 15;
                uint4 val = *(const uint4*)&sT[dd * 136 + mc * 8];
                *(uint4*)(yb + (size_t)dd * SKn + mc * 8) = val;
            }
        }
    }
}

// ---------------------------------------------------------------------------
// Output-projection GEMM v2, head-major K order:
//   out[m][n] = sum_h sum_d aoh[b*16+h][s][d] * woh[h][n][d]
// aoh [bh][s][64] and woh [h][n][64] are both K-major contiguous.
// 64x128 tile -> 512 blocks (2/CU); h-loop(16) x k0 in {0,32}; acc[2][4].
// ---------------------------------------------------------------------------
__global__ __launch_bounds__(256) void gemm_out(
    const unsigned short* __restrict__ aoh,
    const unsigned short* __restrict__ woh,
    float* __restrict__ Y)
{
    __shared__ unsigned short sA[64 * 32];
    __shared__ unsigned short sB[128 * 32];

    const int tid  = threadIdx.x;
    const int wv   = tid >> 6;
    const int lane = tid & 63;
    const int quad = lane >> 4;
    const int l15  = lane & 15;
    const int m0   = blockIdx.x * 64;
    const int n0   = blockIdx.y * 128;
    const int wr   = (wv >> 1) * 32;
    const int wc   = (wv & 1) * 64;
    const int b_   = m0 >> 11;
    const int s0   = m0 & (SQn - 1);

    int aoff[2], boff[4];
#pragma unroll
    for (int i = 0; i < 2; ++i) {
        int row = wr + i * 16 + l15;
        aoff[i] = row * 32 + ((quad ^ SWZ(row)) * 8);
    }
#pragma unroll
    for (int j = 0; j < 4; ++j) {
        int col = wc + j * 16 + l15;
        boff[j] = col * 32 + ((quad ^ SWZ(col)) * 8);
    }

    const int arow = tid >> 2;
    const int acs  = (tid & 3) ^ SWZ(arow);
    int bf_[2], brow[2], bcs[2];
#pragma unroll
    for (int r = 0; r < 2; ++r) {
        int f = r * 256 + tid;
        bf_[r] = f; brow[r] = f >> 2; bcs[r] = (f & 3) ^ SWZ(brow[r]);
    }

    f32x4 acc[2][4];
#pragma unroll
    for (int i = 0; i < 2; ++i)
#pragma unroll
        for (int j = 0; j < 4; ++j)
            acc[i][j] = (f32x4){0.f, 0.f, 0.f, 0.f};

    for (int h = 0; h < NH; ++h) {
        const unsigned short* Ah = aoh + ((size_t)(b_ * NH + h) * SQn + s0) * HD;
        const unsigned short* Bh = woh + ((size_t)h * 1024 + n0) * HD;
#pragma unroll
        for (int k0 = 0; k0 < 64; k0 += 32) {
            __syncthreads();
            gl_lds16(Ah + (size_t)arow * HD + k0 + acs * 8, &sA[tid * 8]);
#pragma unroll
            for (int r = 0; r < 2; ++r)
                gl_lds16(Bh + (size_t)brow[r] * HD + k0 + bcs[r] * 8, &sB[bf_[r] * 8]);
            __syncthreads();

            bf16x8 af[2], bfr[4];
#pragma unroll
            for (int i = 0; i < 2; ++i) af[i]  = *(const bf16x8*)&sA[aoff[i]];
#pragma unroll
            for (int j = 0; j < 4; ++j) bfr[j] = *(const bf16x8*)&sB[boff[j]];
#pragma unroll
            for (int i = 0; i < 2; ++i)
#pragma unroll
                for (int j = 0; j < 4; ++j)
                    acc[i][j] = __builtin_amdgcn_mfma_f32_16x16x32_bf16(af[i], bfr[j], acc[i][j], 0, 0, 0);
        }
    }

#pragma unroll
    for (int i = 0; i < 2; ++i) {
        int mbase = m0 + wr + i * 16 + quad * 4;
#pragma unroll
        for (int j = 0; j < 4; ++j) {
            int col = n0 + wc + j * 16 + l15;
#pragma unroll
            for (int r = 0; r < 4; ++r)
                Y[(size_t)(mbase + r) * DMODEL + col] = acc[i][j][r];
        }
    }
}

// ---------------------------------------------------------------------------
// E (P x D) fp32 -> relTb[h][p][d] bf16, rel[h][p][d] = E[p, d*NH + h]
// ---------------------------------------------------------------------------
__global__ __launch_bounds__(256) void relt_kernel(
    const float* __restrict__ E, unsigned short* __restrict__ relTb)
{
    int idx = blockIdx.x * 256 + threadIdx.x;
    const int total = NH * NPOS * HD;
    if (idx < total) {
        int d = idx & (HD - 1);
        int p = (idx >> 6) % NPOS;
        int h = idx / (NPOS * HD);
        relTb[idx] = f2bf(E[(size_t)p * DMODEL + d * NH + h]);
    }
}

// ---------------------------------------------------------------------------
// MFMA flash-style local attention, v9: v4's proven LDS-staged pipeline,
// 128-row Q SUPERTILE per block (two 64-row strips A/B per staged K/V tile).
// v7 post-mortem: direct-to-register global loads get sunk by the compiler
// (VGPR stayed 64) -> serial L2 latency; only gl_lds staging pipelines.
// v9 keeps v4's per-tile staging/barrier structure verbatim and instead:
//   - strips A/B share each staged K/V tile AND the in-register K frags
//     -> staging traffic + barriers per unit work HALVED, 32 MFMA/wave
//        per barrier-pair (vs 16)
//   - grid 512 = exactly 2 blocks/CU (LDS 57.5KB): one balanced round,
//     no 768+256 straggler round (v4's Occ was 19.7% from the ragged tail)
//   - __expf -> exp2 with log2-folded scales (saves a mul per exp)
// sq8 is 128x260; Q supertile aliases its first 16KB (same liveness proof
// as v4). Single sP reused A-then-B (per-wave DS ordering makes it safe).
// ---------------------------------------------------------------------------
#define BIAS_S2 0.0014089565402528222f   // (1/1024)/ln2
#define SC2     0.1803368801111204f      // 0.125/ln2

__global__ __launch_bounds__(256, 2) void attn_mfma(
    const unsigned short* __restrict__ q,
    const unsigned short* __restrict__ k,
    const unsigned short* __restrict__ vT,
    const unsigned short* __restrict__ relTb,
    unsigned short* __restrict__ aoh)
{
    __shared__ unsigned short sK[64 * 64];     // swizzled K staging
    __shared__ unsigned short sVt[64 * 64];    // swizzled V^T staging
    __shared__ unsigned short sP[4][16 * 72];  // per-wave P tile (A then B)
    __shared__ signed char    sq8[128 * 260];  // int8 bias; first 16KB doubles as sQ
    unsigned short* const sQ = (unsigned short*)sq8;

    const int tid  = threadIdx.x;
    const int w    = tid >> 6;
    const int lane = tid & 63;
    const int quad = lane >> 4;
    const int l15  = lane & 15;
    // XCD-aware block swizzle: 512 blocks = 8 XCD x 4 bh x 16 supertiles
    const int xcd  = blockIdx.x & 7;
    const int sidx = blockIdx.x >> 3;
    const int bh   = (xcd << 2) | (sidx >> 4);
    const int q0   = (sidx & 15) << 7;          // 128-row supertile base
    const int h    = bh & (NH - 1);

    // hoisted staging descriptors (two 16B issues per thread for 64-row tiles)
    const int f1 = tid,       row1 = f1 >> 3;
    const int c1 = ((f1 & 7) ^ (row1 & 7)) * 8;
    const int f2 = 256 + tid, row2 = f2 >> 3;
    const int c2 = ((f2 & 7) ^ (row2 & 7)) * 8;

    // ---- stage Q supertile (128x64, into region later overwritten by sq8) ----
    {
        const unsigned short* gq = q + ((size_t)bh * SQn + q0) * HD;
#pragma unroll
        for (int it = 0; it < 4; ++it) {
            int f = it * 256 + tid;
            int row = f >> 3;
            int c = ((f & 7) ^ (row & 7)) * 8;
            gl_lds16(gq + row * HD + c, &sQ[f * 8]);
        }
    }
    __syncthreads();

    const int qrow = w * 16 + l15;
    const int qs = (quad ^ (qrow & 7)) * 8;     // (row&7) invariant under +64
    bf16x8 a0A = *(const bf16x8*)&sQ[qrow * 64 + qs];
    bf16x8 a1A = *(const bf16x8*)&sQ[qrow * 64 + (qs ^ 32)];
    bf16x8 a0B = *(const bf16x8*)&sQ[(64 + qrow) * 64 + qs];
    bf16x8 a1B = *(const bf16x8*)&sQ[(64 + qrow) * 64 + (qs ^ 32)];

    // ---- qrel phase: int8-encode qrel*0.125 in 1/1024 units, both strips ----
    // (first c5 iteration's barrier pair guarantees every wave has read its
    //  a frags from sQ before any sq8 write lands on the aliased region)
    const int myrow = w * 16 + quad * 4;
    for (int c5 = 0; c5 < 5; ++c5) {
        __syncthreads();
        const unsigned short* gr = relTb + ((size_t)h * NPOS + c5 * 64) * HD;
        gl_lds16(gr + row1 * HD + c1, &sK[f1 * 8]);
        gl_lds16(gr + row2 * HD + c2, &sK[f2 * 8]);
        __syncthreads();
#pragma unroll
        for (int t = 0; t < 4; ++t) {
            int prow = t * 16 + l15;
            int ks = (quad ^ (prow & 7)) * 8;
            bf16x8 b0 = *(const bf16x8*)&sK[prow * 64 + ks];
            bf16x8 b1 = *(const bf16x8*)&sK[prow * 64 + (ks ^ 32)];
            f32x4 ccA = {0.f, 0.f, 0.f, 0.f};
            ccA = __builtin_amdgcn_mfma_f32_16x16x32_bf16(a0A, b0, ccA, 0, 0, 0);
            ccA = __builtin_amdgcn_mfma_f32_16x16x32_bf16(a1A, b1, ccA, 0, 0, 0);
            f32x4 ccB = {0.f, 0.f, 0.f, 0.f};
            ccB = __builtin_amdgcn_mfma_f32_16x16x32_bf16(a0B, b0, ccB, 0, 0, 0);
            ccB = __builtin_amdgcn_mfma_f32_16x16x32_bf16(a1B, b1, ccB, 0, 0, 0);
            int pos = c5 * 64 + t * 16 + l15;
            if (pos < NPOS) {
#pragma unroll
                for (int r = 0; r < 4; ++r) {
                    int iqA = (int)rintf(ccA[r] * 128.0f);
                    iqA = iqA < -127 ? -127 : (iqA > 127 ? 127 : iqA);
                    sq8[(myrow + r) * 260 + pos] = (signed char)iqA;
                    int iqB = (int)rintf(ccB[r] * 128.0f);
                    iqB = iqB < -127 ? -127 : (iqB > 127 ? 127 : iqB);
                    sq8[(64 + myrow + r) * 260 + pos] = (signed char)iqB;
                }
            }
        }
    }
    __syncthreads();

    float bias0A[4], bias256A[4], bias0B[4], bias256B[4];
#pragma unroll
    for (int r = 0; r < 4; ++r) {
        bias0A[r]   = (float)sq8[(myrow + r) * 260 + 0]          * BIAS_S2;
        bias256A[r] = (float)sq8[(myrow + r) * 260 + 256]        * BIAS_S2;
        bias0B[r]   = (float)sq8[(64 + myrow + r) * 260 + 0]     * BIAS_S2;
        bias256B[r] = (float)sq8[(64 + myrow + r) * 260 + 256]   * BIAS_S2;
    }

    // ---- main loop over the UNION window of both strips ----
    const int lo = (q0 - RADIUS) > 0 ? (q0 - RADIUS) : 0;
    const int hi = (q0 + 127 + RADIUS) < (SKn - 1) ? (q0 + 127 + RADIUS) : (SKn - 1);
    const int nt = ((hi - lo) >> 6) + 1;
    const int e_ = l15 - quad * 4;

    const unsigned short* kg = k  + (size_t)bh * SKn * HD;
    const unsigned short* vg = vT + (size_t)bh * HD * SKn;

    float laccA[4] = {0.f, 0.f, 0.f, 0.f};
    float laccB[4] = {0.f, 0.f, 0.f, 0.f};
    f32x4 oA[4], oB[4];
#pragma unroll
    for (int t = 0; t < 4; ++t) {
        oA[t] = (f32x4){0.f, 0.f, 0.f, 0.f};
        oB[t] = (f32x4){0.f, 0.f, 0.f, 0.f};
    }

    // prologue: stage tile 0
    {
        gl_lds16(kg + (size_t)(lo + row1) * HD + c1, &sK[f1 * 8]);
        gl_lds16(kg + (size_t)(lo + row2) * HD + c2, &sK[f2 * 8]);
        gl_lds16(vg + (size_t)row1 * SKn + lo + c1, &sVt[f1 * 8]);
        gl_lds16(vg + (size_t)row2 * SKn + lo + c2, &sVt[f2 * 8]);
    }

    for (int kt = 0; kt < nt; ++kt) {
        const int kb = lo + (kt << 6);
        __syncthreads();      // vmcnt(0) drain: staging for kt complete

        // read ALL frags for this tile into registers (shared by both strips)
        bf16x8 kf0[4], kf1[4], vf0[4], vf1[4];
#pragma unroll
        for (int t = 0; t < 4; ++t) {
            int prow = t * 16 + l15;
            int ks = (quad ^ (prow & 7)) * 8;
            kf0[t] = *(const bf16x8*)&sK[prow * 64 + ks];
            kf1[t] = *(const bf16x8*)&sK[prow * 64 + (ks ^ 32)];
            vf0[t] = *(const bf16x8*)&sVt[prow * 64 + ks];
            vf1[t] = *(const bf16x8*)&sVt[prow * 64 + (ks ^ 32)];
        }
        __syncthreads();      // all waves done reading sK/sVt -> buffers free

        if (kt + 1 < nt) {    // stage kt+1 while we compute kt
            const int kb2 = kb + 64;
            gl_lds16(kg + (size_t)(kb2 + row1) * HD + c1, &sK[f1 * 8]);
            gl_lds16(kg + (size_t)(kb2 + row2) * HD + c2, &sK[f2 * 8]);
            gl_lds16(vg + (size_t)row1 * SKn + kb2 + c1, &sVt[f1 * 8]);
            gl_lds16(vg + (size_t)row2 * SKn + kb2 + c2, &sVt[f2 * 8]);
        }

        // ======== strip A (q rows q0 + w*16 + [0,16)) ========
        const int dtbaseA = kb - q0 - w * 16;
        if (dtbaseA > -320 && dtbaseA < 272) {   // some t in window
#pragma unroll
            for (int t = 0; t < 4; ++t) {
                const int dt = dtbaseA + t * 16;
                const int spb = (quad * 4) * 72 + t * 16 + l15;
                if (dt <= -272 || dt >= 272) {
#pragma unroll
                    for (int r = 0; r < 4; ++r) sP[w][spb + r * 72] = 0;
                } else {
                    f32x4 sc = {0.f, 0.f, 0.f, 0.f};
                    sc = __builtin_amdgcn_mfma_f32_16x16x32_bf16(a0A, kf0[t], sc, 0, 0, 0);
                    sc = __builtin_amdgcn_mfma_f32_16x16x32_bf16(a1A, kf1[t], sc, 0, 0, 0);

                    float pv[4];
                    if (dt >= -112 && dt <= 112) {
                        int idx0 = myrow * 260 + dt + 128 + e_;
#pragma unroll
                        for (int r = 0; r < 4; ++r) {
                            float bf = (float)sq8[idx0 + r * 259] * BIAS_S2;
                            pv[r] = __builtin_amdgcn_exp2f(fmaf(sc[r], SC2, bf));
                        }
                    } else if (dt >= -240 && dt <= -144) {
#pragma unroll
                        for (int r = 0; r < 4; ++r)
                            pv[r] = __builtin_amdgcn_exp2f(fmaf(sc[r], SC2, bias0A[r]));
                    } else if (dt >= 144 && dt <= 240) {
#pragma unroll
                        for (int r = 0; r < 4; ++r)
                            pv[r] = __builtin_amdgcn_exp2f(fmaf(sc[r], SC2, bias256A[r]));
                    } else {    // boundary: mask + clip per element
#pragma unroll
                        for (int r = 0; r < 4; ++r) {
                            int d = dt + e_ - r;
                            bool in = (unsigned)(d + RADIUS) <= 2u * RADIUS;
                            int p = d < -RWIN ? 0 : (d > RWIN ? 2 * RWIN : d + RWIN);
                            float bf = (float)sq8[(myrow + r) * 260 + p] * BIAS_S2;
                            float e = __builtin_amdgcn_exp2f(fmaf(sc[r], SC2, bf));
                            pv[r] = in ? e : 0.0f;
                        }
                    }
#pragma unroll
                    for (int r = 0; r < 4; ++r) {
                        unsigned short pb = f2bf(pv[r]);
                        sP[w][spb + r * 72] = pb;
                        laccA[r] += bf2f(pb);
                    }
                }
            }
            bf16x8 p0 = *(const bf16x8*)&sP[w][l15 * 72 + quad * 8];
            bf16x8 p1 = *(const bf16x8*)&sP[w][l15 * 72 + 32 + quad * 8];
#pragma unroll
            for (int t = 0; t < 4; ++t) {
                oA[t] = __builtin_amdgcn_mfma_f32_16x16x32_bf16(p0, vf0[t], oA[t], 0, 0, 0);
                oA[t] = __builtin_amdgcn_mfma_f32_16x16x32_bf16(p1, vf1[t], oA[t], 0, 0, 0);
            }
        }

        // ======== strip B (q rows q0 + 64 + w*16 + [0,16)) ========
        const int dtbaseB = dtbaseA - 64;
        if (dtbaseB > -320 && dtbaseB < 272) {
#pragma unroll
            for (int t = 0; t < 4; ++t) {
                const int dt = dtbaseB + t * 16;
                const int spb = (quad * 4) * 72 + t * 16 + l15;
                if (dt <= -272 || dt >= 272) {
#pragma unroll
                    for (int r = 0; r < 4; ++r) sP[w][spb + r * 72] = 0;
                } else {
                    f32x4 sc = {0.f, 0.f, 0.f, 0.f};
                    sc = __builtin_amdgcn_mfma_f32_16x16x32_bf16(a0B, kf0[t], sc, 0, 0, 0);
                    sc = __builtin_amdgcn_mfma_f32_16x16x32_bf16(a1B, kf1[t], sc, 0, 0, 0);

                    float pv[4];
                    if (dt >= -112 && dt <= 112) {
                        int idx0 = (64 + myrow) * 260 + dt + 128 + e_;
#pragma unroll
                        for (int r = 0; r < 4; ++r) {
                            float bf = (float)sq8[idx0 + r * 259] * BIAS_S2;
                            pv[r] = __builtin_amdgcn_exp2f(fmaf(sc[r], SC2, bf));
                        }
                    } else if (dt >= -240 && dt <= -144) {
#pragma unroll
                        for (int r = 0; r < 4; ++r)
                            pv[r] = __builtin_amdgcn_exp2f(fmaf(sc[r], SC2, bias0B[r]));
                    } else if (dt >= 144 && dt <= 240) {
#pragma unroll
                        for (int r = 0; r < 4; ++r)
                            pv[r] = __builtin_amdgcn_exp2f(fmaf(sc[r], SC2, bias256B[r]));
                    } else {
#pragma unroll
                        for (int r = 0; r < 4; ++r) {
                            int d = dt + e_ - r;
                            bool in = (unsigned)(d + RADIUS) <= 2u * RADIUS;
                            int p = d < -RWIN ? 0 : (d > RWIN ? 2 * RWIN : d + RWIN);
                            float bf = (float)sq8[(64 + myrow + r) * 260 + p] * BIAS_S2;
                            float e = __builtin_amdgcn_exp2f(fmaf(sc[r], SC2, bf));
                            pv[r] = in ? e : 0.0f;
                        }
                    }
#pragma unroll
                    for (int r = 0; r < 4; ++r) {
                        unsigned short pb = f2bf(pv[r]);
                        sP[w][spb + r * 72] = pb;
                        laccB[r] += bf2f(pb);
                    }
                }
            }
            bf16x8 p0 = *(const bf16x8*)&sP[w][l15 * 72 + quad * 8];
            bf16x8 p1 = *(const bf16x8*)&sP[w][l15 * 72 + 32 + quad * 8];
#pragma unroll
            for (int t = 0; t < 4; ++t) {
                oB[t] = __builtin_amdgcn_mfma_f32_16x16x32_bf16(p0, vf0[t], oB[t], 0, 0, 0);
                oB[t] = __builtin_amdgcn_mfma_f32_16x16x32_bf16(p1, vf1[t], oB[t], 0, 0, 0);
            }
        }
    }

    float linvA[4], linvB[4];
#pragma unroll
    for (int r = 0; r < 4; ++r) {
        float lA = laccA[r];
        float lB = laccB[r];
#pragma unroll
        for (int off = 1; off <= 8; off <<= 1) {
            lA += __shfl_xor(lA, off);
            lB += __shfl_xor(lB, off);
        }
        linvA[r] = 1.0f / lA;
        linvB[r] = 1.0f / lB;
    }

    // epilogue: per-block dense aoh[bh][s][d] (16 KB contiguous per block)
    unsigned short* ob = aoh + ((size_t)bh * SQn + q0) * HD;
#pragma unroll
    for (int t = 0; t < 4; ++t) {
#pragma unroll
        for (int r = 0; r < 4; ++r) {
            int irow = w * 16 + quad * 4 + r;
            ob[irow * HD + t * 16 + l15] = f2bf(oA[t][r] * linvA[r]);
            ob[(64 + irow) * HD + t * 16 + l15] = f2bf(oB[t][r] * linvB[r]);
        }
    }
}

// ---------------------------------------------------------------------------
extern "C" void kernel_launch(void* const* d_in, const int* in_sizes, int n_in,
                              void* d_out, int out_size, void* d_ws, size_t ws_size,
                              hipStream_t stream) {
    const float* Q  = (const float*)d_in[0];
    const float* K  = (const float*)d_in[1];
    const float* V  = (const float*)d_in[2];
    const float* Wq = (const float*)d_in[3];
    const float* Wk = (const float*)d_in[4];
    const float* Wv = (const float*)d_in[5];
    const float* Wo = (const float*)d_in[6];
    const float* E  = (const float*)d_in[7];
    float* out = (float*)d_out;

    char* p = (char*)d_ws;
    unsigned short* xb    = (unsigned short*)p; p += (size_t)24 << 20;  // [3][4M] bf16
    unsigned short* wb    = (unsigned short*)p; p += (size_t)6  << 20;  // [3][1M] bf16
    unsigned short* woh   = (unsigned short*)p; p += (size_t)2  << 20;  // [16][1024][64]
    unsigned short* head  = (unsigned short*)p; p += (size_t)24 << 20;  // q,k,vT bf16
    unsigned short* relTb = (unsigned short*)p; p += (size_t)1  << 20;
    unsigned short* aoh   = (unsigned short*)p;                          // 8 MB

    unsigned short* qb  = head;
    unsigned short* kb  = head + 4194304;
    unsigned short* vTb = head + 8388608;

    dim3 bb(256);
    convert_kernel<<<dim3(16384), bb, 0, stream>>>(Q, K, V, Wq, Wk, Wv, Wo, xb, wb, woh);
    relt_kernel<<<dim3(1028), bb, 0, stream>>>(E, relTb);
    mfma_gemm<<<dim3(32, 8, 3), bb, 0, stream>>>(xb, wb, head);
    attn_mfma<<<dim3(BATCH * NH * (SQn / 128)), bb, 0, stream>>>(qb, kb, vTb, relTb, aoh);
    gemm_out<<<dim3(64, 8), bb, 0, stream>>>(aoh, woh, out);
}

// Round 5
// 204.972 us; speedup vs baseline: 1.1890x; 1.0084x over previous
//
#include <hip/hip_runtime.h>
#include <hip/hip_bf16.h>

// Problem constants
#define BATCH 2
#define SQn 2048
#define SKn 2048
#define DMODEL 1024
#define NH 16
#define HD 64
#define NPOS 257          // 2*128+1
#define RWIN 128          // rel_pos_max_distance
#define RADIUS 256        // local attention radius

typedef __attribute__((ext_vector_type(8))) short bf16x8;
typedef __attribute__((ext_vector_type(4))) float f32x4;

static __device__ __forceinline__ unsigned short f2bf(float f) {
    union { float f; unsigned u; } v; v.f = f;
    unsigned r = (v.u + 0x7FFFu + ((v.u >> 16) & 1u)) >> 16;   // RNE
    return (unsigned short)r;
}
static __device__ __forceinline__ float bf2f(unsigned short b) {
    union { unsigned u; float f; } v; v.u = ((unsigned)b) << 16;
    return v.f;
}

static __device__ __forceinline__ void gl_lds16(const unsigned short* g, unsigned short* l) {
    __builtin_amdgcn_global_load_lds(
        (const __attribute__((address_space(1))) unsigned*)g,
        (__attribute__((address_space(3))) unsigned*)l, 16, 0, 0);
}

// legacy 4-chunk swizzle (BK=32 rows of 4x8 chunks)
#define SWZ(row) (((row) ^ ((row) >> 2)) & 3)

// ---------------------------------------------------------------------------
// Fused fp32 -> bf16 conversion:
//   Q,K,V (3 x 4M) -> xb;  Wq,Wk,Wv (3 x 1M) -> wb;
//   Wo -> woh[h][n][d] = Wo[n][d*16+h]  (head-sliced repack for gemm_out).
// ---------------------------------------------------------------------------
__global__ __launch_bounds__(256) void convert_kernel(
    const float* __restrict__ Q, const float* __restrict__ K, const float* __restrict__ V,
    const float* __restrict__ Wq, const float* __restrict__ Wk, const float* __restrict__ Wv,
    const float* __restrict__ Wo,
    unsigned short* __restrict__ xb,    // [3][4194304]
    unsigned short* __restrict__ wb,    // [3][1048576]
    unsigned short* __restrict__ woh)   // [16][1024][64]
{
    int i = blockIdx.x * 256 + threadIdx.x;     // float4 index, < 4194304
    if (i < 3145728) {
        int which = i >> 20;
        int off = i & 1048575;
        const float* src = which == 0 ? Q : (which == 1 ? K : V);
        unsigned short* dst = xb + (size_t)which * 4194304;
        float4 v4 = ((const float4*)src)[off];
        ushort4 o4;
        o4.x = f2bf(v4.x); o4.y = f2bf(v4.y); o4.z = f2bf(v4.z); o4.w = f2bf(v4.w);
        ((ushort4*)dst)[off] = o4;
    } else {
        int i2 = i - 3145728;
        int which = i2 >> 18;
        int off = i2 & 262143;
        if (which < 3) {
            const float* src = which == 0 ? Wq : (which == 1 ? Wk : Wv);
            unsigned short* dst = wb + (size_t)which * 1048576;
            float4 v4 = ((const float4*)src)[off];
            ushort4 o4;
            o4.x = f2bf(v4.x); o4.y = f2bf(v4.y); o4.z = f2bf(v4.z); o4.w = f2bf(v4.w);
            ((ushort4*)dst)[off] = o4;
        } else {
            // Wo repack: float4 = Wo[n][c0..c0+3], c=d*16+h (4-aligned c0 ->
            // d fixed, h = (c0&15)+j). Scatter 4 ushorts into woh slabs.
            float4 v4 = ((const float4*)Wo)[off];
            int e0 = off * 4;
            int n  = e0 >> 10;
            int c0 = e0 & 1023;
            int d  = c0 >> 4;
            int h0 = c0 & 15;
            woh[((size_t)(h0 + 0) * 1024 + n) * 64 + d] = f2bf(v4.x);
            woh[((size_t)(h0 + 1) * 1024 + n) * 64 + d] = f2bf(v4.y);
            woh[((size_t)(h0 + 2) * 1024 + n) * 64 + d] = f2bf(v4.z);
            woh[((size_t)(h0 + 3) * 1024 + n) * 64 + d] = f2bf(v4.w);
        }
    }
}

// ---------------------------------------------------------------------------
// QKV bf16 MFMA GEMM v2: Y = X(4096x1024) @ W(1024x1024)^T, z slab in {0,1,2}.
// 128x128 tile, BK=64 (was 32): 16 staging rounds instead of 32, 32 MFMA per
// barrier-pair instead of 16 -> halves the vmcnt(0)+barrier drain frequency
// (R4 counters: MfmaUtil 23%, nothing >25% busy -> drain/latency-bound).
// LDS rows of 64 els = 8 chunks of 8; chunk j of row R stored at slot
// j^(R&7) -> frag ds_read_b128 is 2-way bank aliased (free per m136).
// ks0 frags+MFMA issue before the second barrier; stage of round k+1 issues
// before the ks1 MFMA block so staging latency hides under compute.
// z<2 : bf16 head-split [bh][s][hd].  z==2: bf16 [bh][hd][s] via LDS transpose.
// ---------------------------------------------------------------------------
__global__ __launch_bounds__(256) void mfma_gemm(
    const unsigned short* __restrict__ Xall,
    const unsigned short* __restrict__ Wall,
    unsigned short* __restrict__ Yall)
{
    __shared__ unsigned short sA[128 * 64];
    __shared__ unsigned short sB[128 * 64];
    __shared__ unsigned short sT[64 * 136];   // epilogue transpose scratch (z==2)

    const int tid  = threadIdx.x;
    const int wv   = tid >> 6;
    const int lane = tid & 63;
    const int quad = lane >> 4;
    const int l15  = lane & 15;
    const int z    = blockIdx.z;
    const int m0   = blockIdx.x * 128;
    const int n0   = blockIdx.y * 128;
    const int wr   = (wv >> 1) * 64;
    const int wc   = (wv & 1) * 64;

    const unsigned short* X = Xall + (size_t)z * (4096 * 1024);
    const unsigned short* W = Wall + (size_t)z * (1024 * 1024);

    // staging descriptors: 4 x 16B per thread per matrix (128 rows x 64)
    int srow[4], scc[4];
#pragma unroll
    for (int it = 0; it < 4; ++it) {
        int f = it * 256 + tid;
        srow[it] = f >> 3;
        scc[it]  = ((f & 7) ^ (srow[it] & 7)) * 8;
    }

    // frag read offsets: row R, k-sub ks (0/1), quad ->
    //   source chunk (ks*4+quad) lives at slot (ks*4+quad)^(R&7)
    int aoff[2][4], boff[2][4];
#pragma unroll
    for (int ks = 0; ks < 2; ++ks)
#pragma unroll
        for (int t = 0; t < 4; ++t) {
            int R = wr + t * 16 + l15;
            aoff[ks][t] = R * 64 + ((((ks << 2) + quad) ^ (R & 7)) * 8);
            int C = wc + t * 16 + l15;
            boff[ks][t] = C * 64 + ((((ks << 2) + quad) ^ (C & 7)) * 8);
        }

    f32x4 acc[4][4];
#pragma unroll
    for (int i = 0; i < 4; ++i)
#pragma unroll
        for (int j = 0; j < 4; ++j)
            acc[i][j] = (f32x4){0.f, 0.f, 0.f, 0.f};

    // prologue: stage k0 = 0
#pragma unroll
    for (int it = 0; it < 4; ++it) {
        gl_lds16(X + (size_t)(m0 + srow[it]) * 1024 + scc[it], &sA[(it * 256 + tid) * 8]);
        gl_lds16(W + (size_t)(n0 + srow[it]) * 1024 + scc[it], &sB[(it * 256 + tid) * 8]);
    }

    for (int k0 = 0; k0 < 1024; k0 += 64) {
        __syncthreads();      // staging for this round complete

        bf16x8 a0[4], b0[4];
#pragma unroll
        for (int t = 0; t < 4; ++t) a0[t] = *(const bf16x8*)&sA[aoff[0][t]];
#pragma unroll
        for (int t = 0; t < 4; ++t) b0[t] = *(const bf16x8*)&sB[boff[0][t]];
#pragma unroll
        for (int i = 0; i < 4; ++i)
#pragma unroll
            for (int j = 0; j < 4; ++j)
                acc[i][j] = __builtin_amdgcn_mfma_f32_16x16x32_bf16(a0[i], b0[j], acc[i][j], 0, 0, 0);

        bf16x8 a1[4], b1[4];
#pragma unroll
        for (int t = 0; t < 4; ++t) a1[t] = *(const bf16x8*)&sA[aoff[1][t]];
#pragma unroll
        for (int t = 0; t < 4; ++t) b1[t] = *(const bf16x8*)&sB[boff[1][t]];
        __syncthreads();      // all reads done -> buffers free

        if (k0 + 64 < 1024) { // stage next round; latency hides under ks1 MFMA
            const int kn = k0 + 64;
#pragma unroll
            for (int it = 0; it < 4; ++it) {
                gl_lds16(X + (size_t)(m0 + srow[it]) * 1024 + kn + scc[it], &sA[(it * 256 + tid) * 8]);
                gl_lds16(W + (size_t)(n0 + srow[it]) * 1024 + kn + scc[it], &sB[(it * 256 + tid) * 8]);
            }
        }
#pragma unroll
        for (int i = 0; i < 4; ++i)
#pragma unroll
            for (int j = 0; j < 4; ++j)
                acc[i][j] = __builtin_amdgcn_mfma_f32_16x16x32_bf16(a1[i], b1[j], acc[i][j], 0, 0, 0);
    }

    unsigned short* Y = Yall + (size_t)z * (4096 * 1024);
    const int b_ = m0 >> 11;            // batch (tile never straddles)
    const int s0 = m0 & (SQn - 1);

    if (z < 2) {
        // head-split [bh][s][hd] (scattered 2B stores; WRITE_SIZE showed no
        // amplification -> issue cost only, not worth an LDS round-trip)
#pragma unroll
        for (int i = 0; i < 4; ++i) {
            int mbase = s0 + wr + i * 16 + quad * 4;
#pragma unroll
            for (int j = 0; j < 4; ++j) {
                int col = n0 + wc + j * 16 + l15;
                int h = col >> 6, dd = col & 63;
                unsigned short* yb = Y + (((size_t)(b_ * NH + h) * SQn) << 6) + dd;
#pragma unroll
                for (int r = 0; r < 4; ++r)
                    yb[(size_t)(mbase + r) << 6] = f2bf(acc[i][j][r]);
            }
        }
    } else {
        // V: [bh][hd][s] via LDS transpose, coalesced dwordx4 stores.
#pragma unroll
        for (int hh = 0; hh < 2; ++hh) {
            __syncthreads();
            if ((wv & 1) == hh) {
#pragma unroll
                for (int i = 0; i < 4; ++i) {
                    int mloc = wr + i * 16 + quad * 4;
#pragma unroll
                    for (int j = 0; j < 4; ++j) {
                        ushort4 pk;
                        pk.x = f2bf(acc[i][j][0]);
                        pk.y = f2bf(acc[i][j][1]);
                        pk.z = f2bf(acc[i][j][2]);
                        pk.w = f2bf(acc[i][j][3]);
                        *(ushort4*)&sT[(j * 16 + l15) * 136 + mloc] = pk;
                    }
                }
            }
            __syncthreads();
            int h = (n0 >> 6) + hh;
            unsigned short* yb = Y + ((size_t)(b_ * NH + h) * HD) * SKn + s0;
#pragma unroll
            for (int it = 0; it < 4; ++it) {
                int u = it * 256 + tid;
                int dd = u >> 4, mc = u & 15;
                uint4 val = *(const uint4*)&sT[dd * 136 + mc * 8];
                *(uint4*)(yb + (size_t)dd * SKn + mc * 8) = val;
            }
        }
    }
}

// ---------------------------------------------------------------------------
// Output-projection GEMM v3: full HD=64 K-depth per head per round.
//   out[m][n] = sum_h sum_d aoh[b*16+h][s][d] * woh[h][n][d]
// 16 rounds (was 32), attn-v4-style pipeline: sync -> ks0 frags -> 8 MFMA ->
// ks1 frags -> sync -> stage h+1 (overlaps ks1 MFMA + next-round drain).
// 64x128 tile -> 512 blocks (2/CU); acc[2][4].
// ---------------------------------------------------------------------------
__global__ __launch_bounds__(256) void gemm_out(
    const unsigned short* __restrict__ aoh,
    const unsigned short* __restrict__ woh,
    float* __restrict__ Y)
{
    __shared__ unsigned short sA[64 * 64];
    __shared__ unsigned short sB[128 * 64];

    const int tid  = threadIdx.x;
    const int wv   = tid >> 6;
    const int lane = tid & 63;
    const int quad = lane >> 4;
    const int l15  = lane & 15;
    const int m0   = blockIdx.x * 64;
    const int n0   = blockIdx.y * 128;
    const int wr   = (wv >> 1) * 32;
    const int wc   = (wv & 1) * 64;
    const int b_   = m0 >> 11;
    const int s0   = m0 & (SQn - 1);

    // staging descriptors (rows of 64 els = 8 chunks, slot=chunk^(row&7))
    int rowa[2], ca[2];
#pragma unroll
    for (int it = 0; it < 2; ++it) {
        int f = it * 256 + tid;
        rowa[it] = f >> 3;
        ca[it]   = ((f & 7) ^ (rowa[it] & 7)) * 8;
    }
    int rowb[4], cb[4];
#pragma unroll
    for (int it = 0; it < 4; ++it) {
        int f = it * 256 + tid;
        rowb[it] = f >> 3;
        cb[it]   = ((f & 7) ^ (rowb[it] & 7)) * 8;
    }

    // frag read offsets
    int aoff[2][2], boff[2][4];
#pragma unroll
    for (int ks = 0; ks < 2; ++ks) {
#pragma unroll
        for (int i = 0; i < 2; ++i) {
            int R = wr + i * 16 + l15;
            aoff[ks][i] = R * 64 + ((((ks << 2) + quad) ^ (R & 7)) * 8);
        }
#pragma unroll
        for (int j = 0; j < 4; ++j) {
            int C = wc + j * 16 + l15;
            boff[ks][j] = C * 64 + ((((ks << 2) + quad) ^ (C & 7)) * 8);
        }
    }

    f32x4 acc[2][4];
#pragma unroll
    for (int i = 0; i < 2; ++i)
#pragma unroll
        for (int j = 0; j < 4; ++j)
            acc[i][j] = (f32x4){0.f, 0.f, 0.f, 0.f};

    // prologue: stage h = 0
    {
        const unsigned short* Ah = aoh + ((size_t)(b_ * NH) * SQn + s0) * HD;
        const unsigned short* Bh = woh + (size_t)n0 * HD;
#pragma unroll
        for (int it = 0; it < 2; ++it)
            gl_lds16(Ah + (size_t)rowa[it] * HD + ca[it], &sA[(it * 256 + tid) * 8]);
#pragma unroll
        for (int it = 0; it < 4; ++it)
            gl_lds16(Bh + (size_t)rowb[it] * HD + cb[it], &sB[(it * 256 + tid) * 8]);
    }

    for (int h = 0; h < NH; ++h) {
        __syncthreads();      // staging for head h complete

        bf16x8 a0[2], b0[4];
#pragma unroll
        for (int i = 0; i < 2; ++i) a0[i] = *(const bf16x8*)&sA[aoff[0][i]];
#pragma unroll
        for (int j = 0; j < 4; ++j) b0[j] = *(const bf16x8*)&sB[boff[0][j]];
#pragma unroll
        for (int i = 0; i < 2; ++i)
#pragma unroll
            for (int j = 0; j < 4; ++j)
                acc[i][j] = __builtin_amdgcn_mfma_f32_16x16x32_bf16(a0[i], b0[j], acc[i][j], 0, 0, 0);

        bf16x8 a1[2], b1[4];
#pragma unroll
        for (int i = 0; i < 2; ++i) a1[i] = *(const bf16x8*)&sA[aoff[1][i]];
#pragma unroll
        for (int j = 0; j < 4; ++j) b1[j] = *(const bf16x8*)&sB[boff[1][j]];
        __syncthreads();      // all reads done -> buffers free

        if (h + 1 < NH) {     // stage next head; hides under ks1 MFMA
            const unsigned short* Ah = aoh + ((size_t)(b_ * NH + h + 1) * SQn + s0) * HD;
            const unsigned short* Bh = woh + ((size_t)(h + 1) * 1024 + n0) * HD;
#pragma unroll
            for (int it = 0; it < 2; ++it)
                gl_lds16(Ah + (size_t)rowa[it] * HD + ca[it], &sA[(it * 256 + tid) * 8]);
#pragma unroll
            for (int it = 0; it < 4; ++it)
                gl_lds16(Bh + (size_t)rowb[it] * HD + cb[it], &sB[(it * 256 + tid) * 8]);
        }
#pragma unroll
        for (int i = 0; i < 2; ++i)
#pragma unroll
            for (int j = 0; j < 4; ++j)
                acc[i][j] = __builtin_amdgcn_mfma_f32_16x16x32_bf16(a1[i], b1[j], acc[i][j], 0, 0, 0);
    }

#pragma unroll
    for (int i = 0; i < 2; ++i) {
        int mbase = m0 + wr + i * 16 + quad * 4;
#pragma unroll
        for (int j = 0; j < 4; ++j) {
            int col = n0 + wc + j * 16 + l15;
#pragma unroll
            for (int r = 0; r < 4; ++r)
                Y[(size_t)(mbase + r) * DMODEL + col] = acc[i][j][r];
        }
    }
}

// ---------------------------------------------------------------------------
// E (P x D) fp32 -> relTb[h][p][d] bf16, rel[h][p][d] = E[p, d*NH + h]
// ---------------------------------------------------------------------------
__global__ __launch_bounds__(256) void relt_kernel(
    const float* __restrict__ E, unsigned short* __restrict__ relTb)
{
    int idx = blockIdx.x * 256 + threadIdx.x;
    const int total = NH * NPOS * HD;
    if (idx < total) {
        int d = idx & (HD - 1);
        int p = (idx >> 6) % NPOS;
        int h = idx / (NPOS * HD);
        relTb[idx] = f2bf(E[(size_t)p * DMODEL + d * NH + h]);
    }
}

// ---------------------------------------------------------------------------
// MFMA flash-style local attention, v9 (unchanged from R3's winning round):
// 128-row Q supertile per block, two 64-row strips A/B share each staged
// K/V tile and in-register K frags; 512 blocks = 2/CU balanced; exp2-direct.
// ---------------------------------------------------------------------------
#define BIAS_S2 0.0014089565402528222f   // (1/1024)/ln2
#define SC2     0.1803368801111204f      // 0.125/ln2

__global__ __launch_bounds__(256, 2) void attn_mfma(
    const unsigned short* __restrict__ q,
    const unsigned short* __restrict__ k,
    const unsigned short* __restrict__ vT,
    const unsigned short* __restrict__ relTb,
    unsigned short* __restrict__ aoh)
{
    __shared__ unsigned short sK[64 * 64];     // swizzled K staging
    __shared__ unsigned short sVt[64 * 64];    // swizzled V^T staging
    __shared__ unsigned short sP[4][16 * 72];  // per-wave P tile (A then B)
    __shared__ signed char    sq8[128 * 260];  // int8 bias; first 16KB doubles as sQ
    unsigned short* const sQ = (unsigned short*)sq8;

    const int tid  = threadIdx.x;
    const int w    = tid >> 6;
    const int lane = tid & 63;
    const int quad = lane >> 4;
    const int l15  = lane & 15;
    // XCD-aware block swizzle: 512 blocks = 8 XCD x 4 bh x 16 supertiles
    const int xcd  = blockIdx.x & 7;
    const int sidx = blockIdx.x >> 3;
    const int bh   = (xcd << 2) | (sidx >> 4);
    const int q0   = (sidx & 15) << 7;          // 128-row supertile base
    const int h    = bh & (NH - 1);

    // hoisted staging descriptors (two 16B issues per thread for 64-row tiles)
    const int f1 = tid,       row1 = f1 >> 3;
    const int c1 = ((f1 & 7) ^ (row1 & 7)) * 8;
    const int f2 = 256 + tid, row2 = f2 >> 3;
    const int c2 = ((f2 & 7) ^ (row2 & 7)) * 8;

    // ---- stage Q supertile (128x64, into region later overwritten by sq8) ----
    {
        const unsigned short* gq = q + ((size_t)bh * SQn + q0) * HD;
#pragma unroll
        for (int it = 0; it < 4; ++it) {
            int f = it * 256 + tid;
            int row = f >> 3;
            int c = ((f & 7) ^ (row & 7)) * 8;
            gl_lds16(gq + row * HD + c, &sQ[f * 8]);
        }
    }
    __syncthreads();

    const int qrow = w * 16 + l15;
    const int qs = (quad ^ (qrow & 7)) * 8;     // (row&7) invariant under +64
    bf16x8 a0A = *(const bf16x8*)&sQ[qrow * 64 + qs];
    bf16x8 a1A = *(const bf16x8*)&sQ[qrow * 64 + (qs ^ 32)];
    bf16x8 a0B = *(const bf16x8*)&sQ[(64 + qrow) * 64 + qs];
    bf16x8 a1B = *(const bf16x8*)&sQ[(64 + qrow) * 64 + (qs ^ 32)];

    // ---- qrel phase: int8-encode qrel*0.125 in 1/1024 units, both strips ----
    const int myrow = w * 16 + quad * 4;
    for (int c5 = 0; c5 < 5; ++c5) {
        __syncthreads();
        const unsigned short* gr = relTb + ((size_t)h * NPOS + c5 * 64) * HD;
        gl_lds16(gr + row1 * HD + c1, &sK[f1 * 8]);
        gl_lds16(gr + row2 * HD + c2, &sK[f2 * 8]);
        __syncthreads();
#pragma unroll
        for (int t = 0; t < 4; ++t) {
            int prow = t * 16 + l15;
            int ks = (quad ^ (prow & 7)) * 8;
            bf16x8 b0 = *(const bf16x8*)&sK[prow * 64 + ks];
            bf16x8 b1 = *(const bf16x8*)&sK[prow * 64 + (ks ^ 32)];
            f32x4 ccA = {0.f, 0.f, 0.f, 0.f};
            ccA = __builtin_amdgcn_mfma_f32_16x16x32_bf16(a0A, b0, ccA, 0, 0, 0);
            ccA = __builtin_amdgcn_mfma_f32_16x16x32_bf16(a1A, b1, ccA, 0, 0, 0);
            f32x4 ccB = {0.f, 0.f, 0.f, 0.f};
            ccB = __builtin_amdgcn_mfma_f32_16x16x32_bf16(a0B, b0, ccB, 0, 0, 0);
            ccB = __builtin_amdgcn_mfma_f32_16x16x32_bf16(a1B, b1, ccB, 0, 0, 0);
            int pos = c5 * 64 + t * 16 + l15;
            if (pos < NPOS) {
#pragma unroll
                for (int r = 0; r < 4; ++r) {
                    int iqA = (int)rintf(ccA[r] * 128.0f);
                    iqA = iqA < -127 ? -127 : (iqA > 127 ? 127 : iqA);
                    sq8[(myrow + r) * 260 + pos] = (signed char)iqA;
                    int iqB = (int)rintf(ccB[r] * 128.0f);
                    iqB = iqB < -127 ? -127 : (iqB > 127 ? 127 : iqB);
                    sq8[(64 + myrow + r) * 260 + pos] = (signed char)iqB;
                }
            }
        }
    }
    __syncthreads();

    float bias0A[4], bias256A[4], bias0B[4], bias256B[4];
#pragma unroll
    for (int r = 0; r < 4; ++r) {
        bias0A[r]   = (float)sq8[(myrow + r) * 260 + 0]          * BIAS_S2;
        bias256A[r] = (float)sq8[(myrow + r) * 260 + 256]        * BIAS_S2;
        bias0B[r]   = (float)sq8[(64 + myrow + r) * 260 + 0]     * BIAS_S2;
        bias256B[r] = (float)sq8[(64 + myrow + r) * 260 + 256]   * BIAS_S2;
    }

    // ---- main loop over the UNION window of both strips ----
    const int lo = (q0 - RADIUS) > 0 ? (q0 - RADIUS) : 0;
    const int hi = (q0 + 127 + RADIUS) < (SKn - 1) ? (q0 + 127 + RADIUS) : (SKn - 1);
    const int nt = ((hi - lo) >> 6) + 1;
    const int e_ = l15 - quad * 4;

    const unsigned short* kg = k  + (size_t)bh * SKn * HD;
    const unsigned short* vg = vT + (size_t)bh * HD * SKn;

    float laccA[4] = {0.f, 0.f, 0.f, 0.f};
    float laccB[4] = {0.f, 0.f, 0.f, 0.f};
    f32x4 oA[4], oB[4];
#pragma unroll
    for (int t = 0; t < 4; ++t) {
        oA[t] = (f32x4){0.f, 0.f, 0.f, 0.f};
        oB[t] = (f32x4){0.f, 0.f, 0.f, 0.f};
    }

    // prologue: stage tile 0
    {
        gl_lds16(kg + (size_t)(lo + row1) * HD + c1, &sK[f1 * 8]);
        gl_lds16(kg + (size_t)(lo + row2) * HD + c2, &sK[f2 * 8]);
        gl_lds16(vg + (size_t)row1 * SKn + lo + c1, &sVt[f1 * 8]);
        gl_lds16(vg + (size_t)row2 * SKn + lo + c2, &sVt[f2 * 8]);
    }

    for (int kt = 0; kt < nt; ++kt) {
        const int kb = lo + (kt << 6);
        __syncthreads();      // vmcnt(0) drain: staging for kt complete

        // read ALL frags for this tile into registers (shared by both strips)
        bf16x8 kf0[4], kf1[4], vf0[4], vf1[4];
#pragma unroll
        for (int t = 0; t < 4; ++t) {
            int prow = t * 16 + l15;
            int ks = (quad ^ (prow & 7)) * 8;
            kf0[t] = *(const bf16x8*)&sK[prow * 64 + ks];
            kf1[t] = *(const bf16x8*)&sK[prow * 64 + (ks ^ 32)];
            vf0[t] = *(const bf16x8*)&sVt[prow * 64 + ks];
            vf1[t] = *(const bf16x8*)&sVt[prow * 64 + (ks ^ 32)];
        }
        __syncthreads();      // all waves done reading sK/sVt -> buffers free

        if (kt + 1 < nt) {    // stage kt+1 while we compute kt
            const int kb2 = kb + 64;
            gl_lds16(kg + (size_t)(kb2 + row1) * HD + c1, &sK[f1 * 8]);
            gl_lds16(kg + (size_t)(kb2 + row2) * HD + c2, &sK[f2 * 8]);
            gl_lds16(vg + (size_t)row1 * SKn + kb2 + c1, &sVt[f1 * 8]);
            gl_lds16(vg + (size_t)row2 * SKn + kb2 + c2, &sVt[f2 * 8]);
        }

        // ======== strip A (q rows q0 + w*16 + [0,16)) ========
        const int dtbaseA = kb - q0 - w * 16;
        if (dtbaseA > -320 && dtbaseA < 272) {   // some t in window
#pragma unroll
            for (int t = 0; t < 4; ++t) {
                const int dt = dtbaseA + t * 16;
                const int spb = (quad * 4) * 72 + t * 16 + l15;
                if (dt <= -272 || dt >= 272) {
#pragma unroll
                    for (int r = 0; r < 4; ++r) sP[w][spb + r * 72] = 0;
                } else {
                    f32x4 sc = {0.f, 0.f, 0.f, 0.f};
                    sc = __builtin_amdgcn_mfma_f32_16x16x32_bf16(a0A, kf0[t], sc, 0, 0, 0);
                    sc = __builtin_amdgcn_mfma_f32_16x16x32_bf16(a1A, kf1[t], sc, 0, 0, 0);

                    float pv[4];
                    if (dt >= -112 && dt <= 112) {
                        int idx0 = myrow * 260 + dt + 128 + e_;
#pragma unroll
                        for (int r = 0; r < 4; ++r) {
                            float bf = (float)sq8[idx0 + r * 259] * BIAS_S2;
                            pv[r] = __builtin_amdgcn_exp2f(fmaf(sc[r], SC2, bf));
                        }
                    } else if (dt >= -240 && dt <= -144) {
#pragma unroll
                        for (int r = 0; r < 4; ++r)
                            pv[r] = __builtin_amdgcn_exp2f(fmaf(sc[r], SC2, bias0A[r]));
                    } else if (dt >= 144 && dt <= 240) {
#pragma unroll
                        for (int r = 0; r < 4; ++r)
                            pv[r] = __builtin_amdgcn_exp2f(fmaf(sc[r], SC2, bias256A[r]));
                    } else {    // boundary: mask + clip per element
#pragma unroll
                        for (int r = 0; r < 4; ++r) {
                            int d = dt + e_ - r;
                            bool in = (unsigned)(d + RADIUS) <= 2u * RADIUS;
                            int p = d < -RWIN ? 0 : (d > RWIN ? 2 * RWIN : d + RWIN);
                            float bf = (float)sq8[(myrow + r) * 260 + p] * BIAS_S2;
                            float e = __builtin_amdgcn_exp2f(fmaf(sc[r], SC2, bf));
                            pv[r] = in ? e : 0.0f;
                        }
                    }
#pragma unroll
                    for (int r = 0; r < 4; ++r) {
                        unsigned short pb = f2bf(pv[r]);
                        sP[w][spb + r * 72] = pb;
                        laccA[r] += bf2f(pb);
                    }
                }
            }
            bf16x8 p0 = *(const bf16x8*)&sP[w][l15 * 72 + quad * 8];
            bf16x8 p1 = *(const bf16x8*)&sP[w][l15 * 72 + 32 + quad * 8];
#pragma unroll
            for (int t = 0; t < 4; ++t) {
                oA[t] = __builtin_amdgcn_mfma_f32_16x16x32_bf16(p0, vf0[t], oA[t], 0, 0, 0);
                oA[t] = __builtin_amdgcn_mfma_f32_16x16x32_bf16(p1, vf1[t], oA[t], 0, 0, 0);
            }
        }

        // ======== strip B (q rows q0 + 64 + w*16 + [0,16)) ========
        const int dtbaseB = dtbaseA - 64;
        if (dtbaseB > -320 && dtbaseB < 272) {
#pragma unroll
            for (int t = 0; t < 4; ++t) {
                const int dt = dtbaseB + t * 16;
                const int spb = (quad * 4) * 72 + t * 16 + l15;
                if (dt <= -272 || dt >= 272) {
#pragma unroll
                    for (int r = 0; r < 4; ++r) sP[w][spb + r * 72] = 0;
                } else {
                    f32x4 sc = {0.f, 0.f, 0.f, 0.f};
                    sc = __builtin_amdgcn_mfma_f32_16x16x32_bf16(a0B, kf0[t], sc, 0, 0, 0);
                    sc = __builtin_amdgcn_mfma_f32_16x16x32_bf16(a1B, kf1[t], sc, 0, 0, 0);

                    float pv[4];
                    if (dt >= -112 && dt <= 112) {
                        int idx0 = (64 + myrow) * 260 + dt + 128 + e_;
#pragma unroll
                        for (int r = 0; r < 4; ++r) {
                            float bf = (float)sq8[idx0 + r * 259] * BIAS_S2;
                            pv[r] = __builtin_amdgcn_exp2f(fmaf(sc[r], SC2, bf));
                        }
                    } else if (dt >= -240 && dt <= -144) {
#pragma unroll
                        for (int r = 0; r < 4; ++r)
                            pv[r] = __builtin_amdgcn_exp2f(fmaf(sc[r], SC2, bias0B[r]));
                    } else if (dt >= 144 && dt <= 240) {
#pragma unroll
                        for (int r = 0; r < 4; ++r)
                            pv[r] = __builtin_amdgcn_exp2f(fmaf(sc[r], SC2, bias256B[r]));
                    } else {
#pragma unroll
                        for (int r = 0; r < 4; ++r) {
                            int d = dt + e_ - r;
                            bool in = (unsigned)(d + RADIUS) <= 2u * RADIUS;
                            int p = d < -RWIN ? 0 : (d > RWIN ? 2 * RWIN : d + RWIN);
                            float bf = (float)sq8[(64 + myrow + r) * 260 + p] * BIAS_S2;
                            float e = __builtin_amdgcn_exp2f(fmaf(sc[r], SC2, bf));
                            pv[r] = in ? e : 0.0f;
                        }
                    }
#pragma unroll
                    for (int r = 0; r < 4; ++r) {
                        unsigned short pb = f2bf(pv[r]);
                        sP[w][spb + r * 72] = pb;
                        laccB[r] += bf2f(pb);
                    }
                }
            }
            bf16x8 p0 = *(const bf16x8*)&sP[w][l15 * 72 + quad * 8];
            bf16x8 p1 = *(const bf16x8*)&sP[w][l15 * 72 + 32 + quad * 8];
#pragma unroll
            for (int t = 0; t < 4; ++t) {
                oB[t] = __builtin_amdgcn_mfma_f32_16x16x32_bf16(p0, vf0[t], oB[t], 0, 0, 0);
                oB[t] = __builtin_amdgcn_mfma_f32_16x16x32_bf16(p1, vf1[t], oB[t], 0, 0, 0);
            }
        }
    }

    float linvA[4], linvB[4];
#pragma unroll
    for (int r = 0; r < 4; ++r) {
        float lA = laccA[r];
        float lB = laccB[r];
#pragma unroll
        for (int off = 1; off <= 8; off <<= 1) {
            lA += __shfl_xor(lA, off);
            lB += __shfl_xor(lB, off);
        }
        linvA[r] = 1.0f / lA;
        linvB[r] = 1.0f / lB;
    }

    // epilogue: per-block dense aoh[bh][s][d] (16 KB contiguous per block)
    unsigned short* ob = aoh + ((size_t)bh * SQn + q0) * HD;
#pragma unroll
    for (int t = 0; t < 4; ++t) {
#pragma unroll
        for (int r = 0; r < 4; ++r) {
            int irow = w * 16 + quad * 4 + r;
            ob[irow * HD + t * 16 + l15] = f2bf(oA[t][r] * linvA[r]);
            ob[(64 + irow) * HD + t * 16 + l15] = f2bf(oB[t][r] * linvB[r]);
        }
    }
}

// ---------------------------------------------------------------------------
extern "C" void kernel_launch(void* const* d_in, const int* in_sizes, int n_in,
                              void* d_out, int out_size, void* d_ws, size_t ws_size,
                              hipStream_t stream) {
    const float* Q  = (const float*)d_in[0];
    const float* K  = (const float*)d_in[1];
    const float* V  = (const float*)d_in[2];
    const float* Wq = (const float*)d_in[3];
    const float* Wk = (const float*)d_in[4];
    const float* Wv = (const float*)d_in[5];
    const float* Wo = (const float*)d_in[6];
    const float* E  = (const float*)d_in[7];
    float* out = (float*)d_out;

    char* p = (char*)d_ws;
    unsigned short* xb    = (unsigned short*)p; p += (size_t)24 << 20;  // [3][4M] bf16
    unsigned short* wb    = (unsigned short*)p; p += (size_t)6  << 20;  // [3][1M] bf16
    unsigned short* woh   = (unsigned short*)p; p += (size_t)2  << 20;  // [16][1024][64]
    unsigned short* head  = (unsigned short*)p; p += (size_t)24 << 20;  // q,k,vT bf16
    unsigned short* relTb = (unsigned short*)p; p += (size_t)1  << 20;
    unsigned short* aoh   = (unsigned short*)p;                          // 8 MB

    unsigned short* qb  = head;
    unsigned short* kb  = head + 4194304;
    unsigned short* vTb = head + 8388608;

    dim3 bb(256);
    convert_kernel<<<dim3(16384), bb, 0, stream>>>(Q, K, V, Wq, Wk, Wv, Wo, xb, wb, woh);
    relt_kernel<<<dim3(1028), bb, 0, stream>>>(E, relTb);
    mfma_gemm<<<dim3(32, 8, 3), bb, 0, stream>>>(xb, wb, head);
    attn_mfma<<<dim3(BATCH * NH * (SQn / 128)), bb, 0, stream>>>(qb, kb, vTb, relTb, aoh);
    gemm_out<<<dim3(64, 8), bb, 0, stream>>>(aoh, woh, out);
}